// Round 1
// baseline (448.698 us; speedup 1.0000x reference)
//
#include <hip/hip_runtime.h>

#define N_NODES 50000
#define N_EDGES 800000
#define D 64

// ---------------------------------------------------------------------------
// Kernel 1: scatter messages.  64 lanes per edge (one lane per feature dim).
// Reads h[src] row coalesced, atomicAdd into neigh[dst] row.
// ---------------------------------------------------------------------------
__global__ __launch_bounds__(256) void sage_scatter(
    const float* __restrict__ h,
    const int* __restrict__ edge_src,
    const int* __restrict__ edge_dst,
    const float* __restrict__ edge_w,
    float* __restrict__ neigh)
{
    const long long tid = (long long)blockIdx.x * blockDim.x + threadIdx.x;
    const int e = (int)(tid >> 6);     // edge index
    const int d = (int)(tid & 63);     // feature index
    if (e >= N_EDGES) return;
    const int s = edge_src[e];
    const int t = edge_dst[e];
    const float w = edge_w[e];
    atomicAdd(&neigh[(long long)t * D + d], w * h[(long long)s * D + d]);
}

// ---------------------------------------------------------------------------
// Kernel 2: out = relu(h @ Ws^T + bs + neigh @ Wn^T + bn)
// Ws/Wn are [D][D] row-major; out[n][j] = sum_k h[n][k]*Ws[j][k] + ...
// Stage both weights TRANSPOSED in LDS so lane j reads sW[k*D+j]
// (consecutive addresses across the wave -> conflict-free).
// 256 threads = 4 node rows x 64 output cols per block.
// ---------------------------------------------------------------------------
__global__ __launch_bounds__(256) void sage_linear(
    const float* __restrict__ h,
    const float* __restrict__ neigh,
    const float* __restrict__ Ws,
    const float* __restrict__ bs,
    const float* __restrict__ Wn,
    const float* __restrict__ bn,
    float* __restrict__ out)
{
    __shared__ float sWs[D * D];   // transposed: sWs[k*D + j] = Ws[j*D + k]
    __shared__ float sWn[D * D];
    for (int i = threadIdx.x; i < D * D; i += blockDim.x) {
        const int j = i >> 6;      // original row (output col)
        const int k = i & 63;      // original col (input dim)
        sWs[k * D + j] = Ws[i];
        sWn[k * D + j] = Wn[i];
    }
    __syncthreads();

    const int r = threadIdx.x >> 6;        // row within block (0..3)
    const int j = threadIdx.x & 63;        // output feature
    const int n = blockIdx.x * 4 + r;      // node index
    if (n >= N_NODES) return;

    const float* __restrict__ hr = h + (long long)n * D;
    const float* __restrict__ nr = neigh + (long long)n * D;

    float acc = bs[j] + bn[j];
#pragma unroll
    for (int k = 0; k < D; ++k) {
        acc = fmaf(hr[k], sWs[k * D + j], acc);
        acc = fmaf(nr[k], sWn[k * D + j], acc);
    }
    out[(long long)n * D + j] = fmaxf(acc, 0.0f);
}

extern "C" void kernel_launch(void* const* d_in, const int* in_sizes, int n_in,
                              void* d_out, int out_size, void* d_ws, size_t ws_size,
                              hipStream_t stream)
{
    const float* h        = (const float*)d_in[0];
    const int*   edge_src = (const int*)d_in[1];
    const int*   edge_dst = (const int*)d_in[2];
    const float* edge_w   = (const float*)d_in[3];
    const float* W_self   = (const float*)d_in[4];
    const float* b_self   = (const float*)d_in[5];
    const float* W_neigh  = (const float*)d_in[6];
    const float* b_neigh  = (const float*)d_in[7];
    float*       out      = (float*)d_out;

    float* neigh = (float*)d_ws;   // N_NODES * D floats = 12.8 MB

    // zero the accumulation buffer (ws is poisoned to 0xAA before every call)
    hipMemsetAsync(neigh, 0, (size_t)N_NODES * D * sizeof(float), stream);

    // scatter: one 64-lane group per edge
    {
        const long long total = (long long)N_EDGES * 64;
        const int block = 256;
        const int grid = (int)((total + block - 1) / block);
        sage_scatter<<<grid, block, 0, stream>>>(h, edge_src, edge_dst, edge_w, neigh);
    }

    // fused linear + bias + relu
    {
        const int block = 256;
        const int grid = (N_NODES + 3) / 4;
        sage_linear<<<grid, block, 0, stream>>>(h, neigh, W_self, b_self,
                                                W_neigh, b_neigh, out);
    }
}

// Round 2
// 343.066 us; speedup vs baseline: 1.3079x; 1.3079x over previous
//
#include <hip/hip_runtime.h>

#define N_NODES 50000
#define N_EDGES 800000
#define D 64

#define SCAN_T 1024
#define CHUNK ((N_NODES + SCAN_T - 1) / SCAN_T)   // 49

// ---------------------------------------------------------------------------
// ws layout (element = 4 B):
//   edges  : int2[N_EDGES]      @ 0            (6.4 MB, 8B-aligned)
//   neigh  : float[N*D]         @ 2*N_EDGES    (12.8 MB)
//   deg    : int[N_NODES]
//   offs   : int[N_NODES+1]
//   cursor : int[N_NODES]
// total ~19.8 MB. If ws_size is smaller, fall back to atomic scatter.
// ---------------------------------------------------------------------------

// ---------------- CSR build ----------------
__global__ __launch_bounds__(256) void hist_kernel(
    const int* __restrict__ dst, int* __restrict__ deg)
{
    const int e = blockIdx.x * 256 + threadIdx.x;
    if (e < N_EDGES) atomicAdd(&deg[dst[e]], 1);
}

__global__ __launch_bounds__(SCAN_T) void scan_kernel(
    const int* __restrict__ deg, int* __restrict__ offs, int* __restrict__ cursor)
{
    __shared__ int part[SCAN_T];
    const int t = threadIdx.x;
    const int b0 = t * CHUNK;
    const int b1 = min(b0 + CHUNK, N_NODES);
    int s = 0;
    for (int i = b0; i < b1; ++i) s += deg[i];
    part[t] = s;
    __syncthreads();
    // Hillis-Steele inclusive scan over 1024 partials
    for (int off = 1; off < SCAN_T; off <<= 1) {
        int v = (t >= off) ? part[t - off] : 0;
        __syncthreads();
        part[t] += v;
        __syncthreads();
    }
    int ex = part[t] - s;      // exclusive prefix for this chunk
    for (int i = b0; i < b1; ++i) {
        offs[i]   = ex;
        cursor[i] = ex;
        ex += deg[i];
    }
    if (t == 0) offs[N_NODES] = N_EDGES;
}

__global__ __launch_bounds__(256) void fill_kernel(
    const int* __restrict__ src, const int* __restrict__ dst,
    const float* __restrict__ w, int* __restrict__ cursor,
    int2* __restrict__ edges)
{
    const int e = blockIdx.x * 256 + threadIdx.x;
    if (e < N_EDGES) {
        const int d = dst[e];
        const int p = atomicAdd(&cursor[d], 1);
        edges[p] = make_int2(src[e], __float_as_int(w[e]));
    }
}

// ---------------- gather: one wave per node, lane = feature dim ----------------
__global__ __launch_bounds__(256) void gather_kernel(
    const float* __restrict__ h, const int2* __restrict__ edges,
    const int* __restrict__ offs, float* __restrict__ neigh)
{
    const int wave = (blockIdx.x * 256 + threadIdx.x) >> 6;   // node id
    const int lane = threadIdx.x & 63;
    if (wave >= N_NODES) return;
    const int beg = offs[wave];
    const int end = offs[wave + 1];
    float acc = 0.f;
    int e = beg;
    // 4-deep pipeline: 4 independent h-row loads in flight per wave
    for (; e + 4 <= end; e += 4) {
        const int2 e0 = edges[e], e1 = edges[e + 1], e2 = edges[e + 2], e3 = edges[e + 3];
        const float v0 = h[(size_t)e0.x * D + lane];
        const float v1 = h[(size_t)e1.x * D + lane];
        const float v2 = h[(size_t)e2.x * D + lane];
        const float v3 = h[(size_t)e3.x * D + lane];
        acc = fmaf(__int_as_float(e0.y), v0, acc);
        acc = fmaf(__int_as_float(e1.y), v1, acc);
        acc = fmaf(__int_as_float(e2.y), v2, acc);
        acc = fmaf(__int_as_float(e3.y), v3, acc);
    }
    for (; e < end; ++e) {
        const int2 ed = edges[e];
        acc = fmaf(__int_as_float(ed.y), h[(size_t)ed.x * D + lane], acc);
    }
    neigh[(size_t)wave * D + lane] = acc;
}

// ---------------- linear: register-held weight rows, readlane broadcast ----------------
__device__ __forceinline__ float lane_bcast(float v, int l) {
    return __int_as_float(__builtin_amdgcn_readlane(__float_as_int(v), l));
}

__global__ __launch_bounds__(256, 2) void linear_kernel(
    const float* __restrict__ h, const float* __restrict__ neigh,
    const float* __restrict__ Ws, const float* __restrict__ bs,
    const float* __restrict__ Wn, const float* __restrict__ bn,
    float* __restrict__ out)
{
    const int lane   = threadIdx.x & 63;
    const int gwave  = (blockIdx.x * blockDim.x + threadIdx.x) >> 6;
    const int nwaves = (gridDim.x * blockDim.x) >> 6;

    // lane j holds row j of both weight matrices (out[j] = sum_k x[k]*W[j][k])
    float Wsr[D], Wnr[D];
#pragma unroll
    for (int k = 0; k < D; k += 4) {
        const float4 a = *(const float4*)&Ws[(size_t)lane * D + k];
        const float4 b = *(const float4*)&Wn[(size_t)lane * D + k];
        Wsr[k] = a.x; Wsr[k+1] = a.y; Wsr[k+2] = a.z; Wsr[k+3] = a.w;
        Wnr[k] = b.x; Wnr[k+1] = b.y; Wnr[k+2] = b.z; Wnr[k+3] = b.w;
    }
    const float bias = bs[lane] + bn[lane];

    for (int n = gwave; n < N_NODES; n += nwaves) {
        const float hv = h[(size_t)n * D + lane];
        const float nv = neigh[(size_t)n * D + lane];
        float o = bias;
#pragma unroll
        for (int k = 0; k < D; ++k) {
            o = fmaf(lane_bcast(hv, k), Wsr[k], o);
            o = fmaf(lane_bcast(nv, k), Wnr[k], o);
        }
        out[(size_t)n * D + lane] = fmaxf(o, 0.f);
    }
}

// ---------------- fallback (ws too small): atomic scatter ----------------
__global__ __launch_bounds__(256) void sage_scatter(
    const float* __restrict__ h,
    const int* __restrict__ edge_src,
    const int* __restrict__ edge_dst,
    const float* __restrict__ edge_w,
    float* __restrict__ neigh)
{
    const long long tid = (long long)blockIdx.x * blockDim.x + threadIdx.x;
    const int e = (int)(tid >> 6);
    const int d = (int)(tid & 63);
    if (e >= N_EDGES) return;
    atomicAdd(&neigh[(long long)edge_dst[e] * D + d],
              edge_w[e] * h[(long long)edge_src[e] * D + d]);
}

extern "C" void kernel_launch(void* const* d_in, const int* in_sizes, int n_in,
                              void* d_out, int out_size, void* d_ws, size_t ws_size,
                              hipStream_t stream)
{
    const float* h        = (const float*)d_in[0];
    const int*   edge_src = (const int*)d_in[1];
    const int*   edge_dst = (const int*)d_in[2];
    const float* edge_w   = (const float*)d_in[3];
    const float* W_self   = (const float*)d_in[4];
    const float* b_self   = (const float*)d_in[5];
    const float* W_neigh  = (const float*)d_in[6];
    const float* b_neigh  = (const float*)d_in[7];
    float*       out      = (float*)d_out;

    // ws layout
    int2*  edges  = (int2*)d_ws;                                  // N_EDGES int2
    float* neigh  = (float*)d_ws + (size_t)2 * N_EDGES;           // N*D floats
    int*   deg    = (int*)(neigh + (size_t)N_NODES * D);          // N
    int*   offs   = deg + N_NODES;                                // N+1
    int*   cursor = offs + N_NODES + 1;                           // N
    const size_t needed = ((size_t)2 * N_EDGES + (size_t)N_NODES * D
                           + 3 * (size_t)N_NODES + 1) * 4;

    if (ws_size >= needed) {
        // --- CSR build ---
        hipMemsetAsync(deg, 0, (size_t)N_NODES * sizeof(int), stream);
        hist_kernel<<<(N_EDGES + 255) / 256, 256, 0, stream>>>(edge_dst, deg);
        scan_kernel<<<1, SCAN_T, 0, stream>>>(deg, offs, cursor);
        fill_kernel<<<(N_EDGES + 255) / 256, 256, 0, stream>>>(
            edge_src, edge_dst, edge_w, cursor, edges);
        // --- gather: one wave per node ---
        gather_kernel<<<(N_NODES + 3) / 4, 256, 0, stream>>>(h, edges, offs, neigh);
    } else {
        float* neigh_fb = (float*)d_ws;
        hipMemsetAsync(neigh_fb, 0, (size_t)N_NODES * D * sizeof(float), stream);
        const long long total = (long long)N_EDGES * 64;
        sage_scatter<<<(int)((total + 255) / 256), 256, 0, stream>>>(
            h, edge_src, edge_dst, edge_w, neigh_fb);
        neigh = neigh_fb;
    }

    // --- fused linear + bias + relu ---
    linear_kernel<<<1024, 256, 0, stream>>>(h, neigh, W_self, b_self,
                                            W_neigh, b_neigh, out);
}

// Round 3
// 246.098 us; speedup vs baseline: 1.8233x; 1.3940x over previous
//
#include <hip/hip_runtime.h>

#define N_NODES 50000
#define N_EDGES 800000
#define D 64

#define SBLK 256
#define NBLKS ((N_NODES + SBLK - 1) / SBLK)   // 196

// ---------------------------------------------------------------------------
// ws layout (element = 4 B):
//   edges  : int2[N_EDGES]      @ 0            (6.4 MB, 8B-aligned)
//   neigh  : float[N*D]                        (12.8 MB)
//   deg    : int[N_NODES]
//   offs   : int[N_NODES+1]
//   cursor : int[N_NODES]
//   bsum   : int[NBLKS]
//   bpref  : int[NBLKS]
// total ~19.8 MB. If ws_size is smaller, fall back to atomic scatter.
// ---------------------------------------------------------------------------

// ---------------- CSR build ----------------
__global__ __launch_bounds__(256) void hist_kernel(
    const int* __restrict__ dst, int* __restrict__ deg)
{
    const int e = blockIdx.x * 256 + threadIdx.x;
    if (e < N_EDGES) atomicAdd(&deg[dst[e]], 1);
}

// per-block sum of deg -> bsum[block]
__global__ __launch_bounds__(SBLK) void block_sum_kernel(
    const int* __restrict__ deg, int* __restrict__ bsum)
{
    const int i = blockIdx.x * SBLK + threadIdx.x;
    int v = (i < N_NODES) ? deg[i] : 0;
#pragma unroll
    for (int off = 32; off >= 1; off >>= 1) v += __shfl_down(v, off, 64);
    __shared__ int ws[SBLK / 64];
    const int wave = threadIdx.x >> 6;
    if ((threadIdx.x & 63) == 0) ws[wave] = v;
    __syncthreads();
    if (threadIdx.x == 0) {
        int s = 0;
#pragma unroll
        for (int w = 0; w < SBLK / 64; ++w) s += ws[w];
        bsum[blockIdx.x] = s;
    }
}

// exclusive scan of bsum[NBLKS] -> bpref[NBLKS]  (single block)
__global__ __launch_bounds__(256) void scan_partials_kernel(
    const int* __restrict__ bsum, int* __restrict__ bpref)
{
    __shared__ int part[256];
    const int t = threadIdx.x;
    const int v = (t < NBLKS) ? bsum[t] : 0;
    part[t] = v;
    __syncthreads();
    for (int off = 1; off < 256; off <<= 1) {
        int p = (t >= off) ? part[t - off] : 0;
        __syncthreads();
        part[t] += p;
        __syncthreads();
    }
    if (t < NBLKS) bpref[t] = part[t] - v;   // exclusive
}

// per-block exclusive scan + block prefix -> offs, cursor
__global__ __launch_bounds__(SBLK) void block_scan_kernel(
    const int* __restrict__ deg, const int* __restrict__ bpref,
    int* __restrict__ offs, int* __restrict__ cursor)
{
    __shared__ int part[SBLK];
    const int i = blockIdx.x * SBLK + threadIdx.x;
    const int t = threadIdx.x;
    const int v = (i < N_NODES) ? deg[i] : 0;
    part[t] = v;
    __syncthreads();
    for (int off = 1; off < SBLK; off <<= 1) {
        int p = (t >= off) ? part[t - off] : 0;
        __syncthreads();
        part[t] += p;
        __syncthreads();
    }
    if (i < N_NODES) {
        const int ex = bpref[blockIdx.x] + part[t] - v;
        offs[i]   = ex;
        cursor[i] = ex;
    }
    if (i == 0) offs[N_NODES] = N_EDGES;
}

__global__ __launch_bounds__(256) void fill_kernel(
    const int* __restrict__ src, const int* __restrict__ dst,
    const float* __restrict__ w, int* __restrict__ cursor,
    int2* __restrict__ edges)
{
    const int e = blockIdx.x * 256 + threadIdx.x;
    if (e < N_EDGES) {
        const int d = dst[e];
        const int p = atomicAdd(&cursor[d], 1);
        edges[p] = make_int2(src[e], __float_as_int(w[e]));
    }
}

// ---------------- gather: one wave per node, lane = feature dim ----------------
__global__ __launch_bounds__(256) void gather_kernel(
    const float* __restrict__ h, const int2* __restrict__ edges,
    const int* __restrict__ offs, float* __restrict__ neigh)
{
    const int wave = (blockIdx.x * 256 + threadIdx.x) >> 6;   // node id
    const int lane = threadIdx.x & 63;
    if (wave >= N_NODES) return;
    const int beg = offs[wave];
    const int end = offs[wave + 1];
    float acc = 0.f;
    int e = beg;
    // 4-deep pipeline: 4 independent h-row loads in flight per wave
    for (; e + 4 <= end; e += 4) {
        const int2 e0 = edges[e], e1 = edges[e + 1], e2 = edges[e + 2], e3 = edges[e + 3];
        const float v0 = h[(size_t)e0.x * D + lane];
        const float v1 = h[(size_t)e1.x * D + lane];
        const float v2 = h[(size_t)e2.x * D + lane];
        const float v3 = h[(size_t)e3.x * D + lane];
        acc = fmaf(__int_as_float(e0.y), v0, acc);
        acc = fmaf(__int_as_float(e1.y), v1, acc);
        acc = fmaf(__int_as_float(e2.y), v2, acc);
        acc = fmaf(__int_as_float(e3.y), v3, acc);
    }
    for (; e < end; ++e) {
        const int2 ed = edges[e];
        acc = fmaf(__int_as_float(ed.y), h[(size_t)ed.x * D + lane], acc);
    }
    neigh[(size_t)wave * D + lane] = acc;
}

// ---------------- linear: register-held weight rows, readlane broadcast ----------------
__device__ __forceinline__ float lane_bcast(float v, int l) {
    return __int_as_float(__builtin_amdgcn_readlane(__float_as_int(v), l));
}

__global__ __launch_bounds__(256, 2) void linear_kernel(
    const float* __restrict__ h, const float* __restrict__ neigh,
    const float* __restrict__ Ws, const float* __restrict__ bs,
    const float* __restrict__ Wn, const float* __restrict__ bn,
    float* __restrict__ out)
{
    const int lane   = threadIdx.x & 63;
    const int gwave  = (blockIdx.x * blockDim.x + threadIdx.x) >> 6;
    const int nwaves = (gridDim.x * blockDim.x) >> 6;

    // lane j holds row j of both weight matrices (out[j] = sum_k x[k]*W[j][k])
    float Wsr[D], Wnr[D];
#pragma unroll
    for (int k = 0; k < D; k += 4) {
        const float4 a = *(const float4*)&Ws[(size_t)lane * D + k];
        const float4 b = *(const float4*)&Wn[(size_t)lane * D + k];
        Wsr[k] = a.x; Wsr[k+1] = a.y; Wsr[k+2] = a.z; Wsr[k+3] = a.w;
        Wnr[k] = b.x; Wnr[k+1] = b.y; Wnr[k+2] = b.z; Wnr[k+3] = b.w;
    }
    const float bias = bs[lane] + bn[lane];

    for (int n = gwave; n < N_NODES; n += nwaves) {
        const float hv = h[(size_t)n * D + lane];
        const float nv = neigh[(size_t)n * D + lane];
        float o = bias;
#pragma unroll
        for (int k = 0; k < D; ++k) {
            o = fmaf(lane_bcast(hv, k), Wsr[k], o);
            o = fmaf(lane_bcast(nv, k), Wnr[k], o);
        }
        out[(size_t)n * D + lane] = fmaxf(o, 0.f);
    }
}

// ---------------- fallback (ws too small): atomic scatter ----------------
__global__ __launch_bounds__(256) void sage_scatter(
    const float* __restrict__ h,
    const int* __restrict__ edge_src,
    const int* __restrict__ edge_dst,
    const float* __restrict__ edge_w,
    float* __restrict__ neigh)
{
    const long long tid = (long long)blockIdx.x * blockDim.x + threadIdx.x;
    const int e = (int)(tid >> 6);
    const int d = (int)(tid & 63);
    if (e >= N_EDGES) return;
    atomicAdd(&neigh[(long long)edge_dst[e] * D + d],
              edge_w[e] * h[(long long)edge_src[e] * D + d]);
}

extern "C" void kernel_launch(void* const* d_in, const int* in_sizes, int n_in,
                              void* d_out, int out_size, void* d_ws, size_t ws_size,
                              hipStream_t stream)
{
    const float* h        = (const float*)d_in[0];
    const int*   edge_src = (const int*)d_in[1];
    const int*   edge_dst = (const int*)d_in[2];
    const float* edge_w   = (const float*)d_in[3];
    const float* W_self   = (const float*)d_in[4];
    const float* b_self   = (const float*)d_in[5];
    const float* W_neigh  = (const float*)d_in[6];
    const float* b_neigh  = (const float*)d_in[7];
    float*       out      = (float*)d_out;

    // ws layout
    int2*  edges  = (int2*)d_ws;                                  // N_EDGES int2
    float* neigh  = (float*)d_ws + (size_t)2 * N_EDGES;           // N*D floats
    int*   deg    = (int*)(neigh + (size_t)N_NODES * D);          // N
    int*   offs   = deg + N_NODES;                                // N+1
    int*   cursor = offs + N_NODES + 1;                           // N
    int*   bsum   = cursor + N_NODES;                             // NBLKS
    int*   bpref  = bsum + NBLKS;                                 // NBLKS
    const size_t needed = ((size_t)2 * N_EDGES + (size_t)N_NODES * D
                           + 3 * (size_t)N_NODES + 1 + 2 * NBLKS) * 4;

    if (ws_size >= needed) {
        // --- CSR build ---
        hipMemsetAsync(deg, 0, (size_t)N_NODES * sizeof(int), stream);
        hist_kernel<<<(N_EDGES + 255) / 256, 256, 0, stream>>>(edge_dst, deg);
        block_sum_kernel<<<NBLKS, SBLK, 0, stream>>>(deg, bsum);
        scan_partials_kernel<<<1, 256, 0, stream>>>(bsum, bpref);
        block_scan_kernel<<<NBLKS, SBLK, 0, stream>>>(deg, bpref, offs, cursor);
        fill_kernel<<<(N_EDGES + 255) / 256, 256, 0, stream>>>(
            edge_src, edge_dst, edge_w, cursor, edges);
        // --- gather: one wave per node ---
        gather_kernel<<<(N_NODES + 3) / 4, 256, 0, stream>>>(h, edges, offs, neigh);
    } else {
        float* neigh_fb = (float*)d_ws;
        hipMemsetAsync(neigh_fb, 0, (size_t)N_NODES * D * sizeof(float), stream);
        const long long total = (long long)N_EDGES * 64;
        sage_scatter<<<(int)((total + 255) / 256), 256, 0, stream>>>(
            h, edge_src, edge_dst, edge_w, neigh_fb);
        neigh = neigh_fb;
    }

    // --- fused linear + bias + relu ---
    linear_kernel<<<1024, 256, 0, stream>>>(h, neigh, W_self, b_self,
                                            W_neigh, b_neigh, out);
}